// Round 1
// 190.228 us; speedup vs baseline: 1.0658x; 1.0658x over previous
//
#include <hip/hip_runtime.h>
#include <hip/hip_bf16.h>
#include <stdint.h>

// ModulatedConv2d: N=16, IC=OC=256, H=W=64, K=3, STYLE=512. fp32 in/out.
// out = demod[n,oc] * conv2d( x * (1+s)[n,ic], weight )   (StyleGAN2 identity)
// R5: k_conv rewritten as 256x256-tile 8-phase schedule (T2+T3+T4+T5):
//     quadrant rotation, counted vmcnt(4) (never 0 in main loop), raw
//     s_barrier, setprio around MFMA. prep2 LDS transpose XOR-swizzled
//     (was ~32-way write conflict).

#define NB  16
#define IC  256
#define OC  256
#define HW  64
#define HWP 66
#define SD  512
#define SPATIAL 4096
#define HWPIC 16896   // HWP*IC

typedef __hip_bfloat16 bf16;
typedef __bf16 bf16x8 __attribute__((ext_vector_type(8)));
typedef float  f32x4  __attribute__((ext_vector_type(4)));
typedef uint32_t u32a3 __attribute__((address_space(3)));
typedef const uint32_t u32a1 __attribute__((address_space(1)));

static __device__ __forceinline__ unsigned short f2bu(float f) {
    bf16 h = __float2bfloat16(f);
    union { bf16 b; unsigned short u; } c; c.b = h; return c.u;
}
static __device__ __forceinline__ void gll16(const void* g, void* l) {
    __builtin_amdgcn_global_load_lds((u32a1*)g, (u32a3*)l, 16, 0, 0);
}

// --- P1: fused prep. blocks [0,256): wt2/wsq; [256,784): border; [784,1808): scale
__global__ __launch_bounds__(256)
void k_prep1(const float* __restrict__ weight, const float* __restrict__ style,
             const float* __restrict__ mod_w, const float* __restrict__ mod_b,
             float* __restrict__ wsq, bf16* __restrict__ wt2,
             uint4* __restrict__ xs4, float* __restrict__ scale) {
    int b = blockIdx.x, t = threadIdx.x;
    if (b < 256) {
        // wsq[oc,ic] = sum_r w^2 ; wt2[r][oc][ic] = bf16(w)
        int tid = b * 256 + t;
        const float* wp = weight + (size_t)tid * 9;
        float v[9], s = 0.f;
        #pragma unroll
        for (int r = 0; r < 9; ++r) { v[r] = wp[r]; s += v[r] * v[r]; }
        wsq[tid] = s;
        #pragma unroll
        for (int r = 0; r < 9; ++r) wt2[(r << 16) + tid] = __float2bfloat16(v[r]);
    } else if (b < 784) {
        // zero 1-px border ring of padded NHWC xs
        int idx = b - 256;
        int n = idx / 33, bx = idx - n * 33;
        int f = bx * 256 + t;
        int u = f >> 5, q = f & 31;
        if (u >= 260) return;
        int rb;
        if      (u <  66) rb = u;
        else if (u < 132) rb = 65 * 66 + (u - 66);
        else if (u < 196) rb = (u - 131) * 66;
        else              rb = (u - 195) * 66 + 65;
        xs4[(size_t)n * 139392 + rb * 32 + q] = make_uint4(0u, 0u, 0u, 0u);
    } else {
        // scale[n,ic] = 1 + style[n,:].mod_w[ic,:] + mod_b[ic]; one wave/output
        int lane = t & 63;
        int w = (b - 784) * 4 + (t >> 6);
        int n = w >> 8, ic = w & 255;
        const float4* mw4 = (const float4*)mod_w + (size_t)ic * 128 + lane * 2;
        const float4* st4 = (const float4*)style + (size_t)n * 128 + lane * 2;
        float4 a0 = mw4[0], a1 = mw4[1], s0 = st4[0], s1 = st4[1];
        float acc = a0.x*s0.x + a0.y*s0.y + a0.z*s0.z + a0.w*s0.w
                  + a1.x*s1.x + a1.y*s1.y + a1.z*s1.z + a1.w*s1.w;
        #pragma unroll
        for (int off = 32; off > 0; off >>= 1) acc += __shfl_down(acc, off);
        if (lane == 0) scale[w] = acc + mod_b[ic] + 1.0f;
    }
}

// --- P2: blocks [0,1024): xs modulate+transpose; [1024,1040): demod ---------
// Transpose tile swizzled: ushort index sp*256 + (ic ^ ((sp>>2&7)<<3)).
// Write banks: <=4-way (was ~32-way with the padded-stride layout);
// reads un-swizzle per 16B seg (alignment preserved).
__global__ __launch_bounds__(256)
void k_prep2(const float* __restrict__ x, const float* __restrict__ scale,
             const float* __restrict__ wsq, bf16* __restrict__ xs,
             float* __restrict__ demod) {
    __shared__ unsigned short tile[HW * 256];   // 32 KB; reused by demod path
    int b = blockIdx.x, t = threadIdx.x;
    if (b < 1024) {
        int y = b & 63, n = b >> 6;
        const float* sc = scale + n * IC;
        const float4* xp4 = (const float4*)(x + ((size_t)n * IC) * SPATIAL + (size_t)y * HW);
        #pragma unroll
        for (int i = 0; i < 16; ++i) {
            int fid = i * 256 + t;
            int ic = fid >> 4, f4 = fid & 15;
            float4 v = xp4[(size_t)ic * 1024 + f4];
            float s = sc[ic];
            int sp = f4 << 2;
            int sw = ic ^ ((f4 & 7) << 3);      // (sp>>2)&7 == f4&7 for all 4 rows
            tile[(sp + 0) * 256 + sw] = f2bu(v.x * s);
            tile[(sp + 1) * 256 + sw] = f2bu(v.y * s);
            tile[(sp + 2) * 256 + sw] = f2bu(v.z * s);
            tile[(sp + 3) * 256 + sw] = f2bu(v.w * s);
        }
        __syncthreads();
        uint4* dst4 = (uint4*)(xs + (((size_t)n * HWP + (y + 1)) * HWP + 1) * IC);
        #pragma unroll
        for (int j = 0; j < 8; ++j) {
            int uid = j * 256 + t;
            int sp = uid >> 5, g = uid & 31;
            dst4[sp * 32 + g] =
                *(const uint4*)&tile[sp * 256 + ((g ^ ((sp >> 2) & 7)) << 3)];
        }
    } else {
        // demod[n,oc] = rsqrt( sum_ic wsq[oc,ic]*scale[n,ic]^2 + eps )
        int n = b - 1024, oc = t;
        float* sc = (float*)tile;
        sc[t] = scale[n * IC + t];
        __syncthreads();
        const float4* wp4 = (const float4*)(wsq + (size_t)oc * IC);
        const float4* sc4 = (const float4*)sc;
        float acc = 0.f;
        #pragma unroll 8
        for (int i = 0; i < 64; ++i) {
            float4 q = wp4[i], s = sc4[i];
            acc += q.x*s.x*s.x + q.y*s.y*s.y + q.z*s.z*s.z + q.w*s.w*s.w;
        }
        demod[n * OC + oc] = rsqrtf(acc + 1e-8f);
    }
}

// --- K7: implicit-GEMM conv, 256x256 tile, BK=64, 8 waves (2Mx4N), 8-phase.
// LDS 128 KiB dynamic: A[par][half][128 rows][64 k] + B same. XOR-seg swizzle
// (LDS seg s holds global seg s^(row&7)) carried over from R4 -> conflict-free
// ds_read_b128. Quadrant rotation per phase: (A0,B0)(A0,B1)(A1,B1)(A1,B0);
// tile t stages tile t+1's half-tiles one per phase (A0,B0,B1,A1) into the
// OTHER buffer parity (never read by tile t -> no slot hazard). vmcnt(4) at
// phase ends p0/p1/p3 guarantees each half-tile landed exactly when first
// read (2-phase slack); never drains to 0 in the main loop.
#define VM4 asm volatile("s_waitcnt vmcnt(4)" ::: "memory")
#define VM2 asm volatile("s_waitcnt vmcnt(2)" ::: "memory")
#define VM0 asm volatile("s_waitcnt vmcnt(0)" ::: "memory")
#define BAR __builtin_amdgcn_s_barrier()

__global__ __launch_bounds__(512, 2)
void k_conv(const bf16* __restrict__ xs, const bf16* __restrict__ wt2,
            const float* __restrict__ demod, float* __restrict__ out) {
    extern __shared__ char smem[];              // 128 KiB
    int t = threadIdx.x, l = t & 63, w = t >> 6;
    int wm = w & 1, wn = w >> 1;
    int bid = blockIdx.x;
    int work = ((bid & 7) << 5) | (bid >> 3);   // XCD-contiguous: xcd*32 + slot
    int nimg = work >> 4;
    int ybase = (work & 15) << 2;               // 4 image rows per tile
    int spb = (work & 15) << 8;                 // 256 spatial positions

    // staging: half-tile = 128 rows x 64 k; load j in {0,1}; wave w, lane l ->
    // row = j*64 + w*8 + (l>>3), LDS seg l&7 holds global seg (l&7)^(l>>3).
    int srow = (w << 3) + (l >> 3);             // 0..63
    int gseg = (l & 7) ^ (l >> 3);
    const bf16* gA = xs + (((size_t)nimg * HWP + ybase) * HWP + srow) * IC + (gseg << 3);
    const bf16* gB = wt2 + ((size_t)srow << 8) + (gseg << 3);
    int stW = w << 10;                          // wave byte offset in half-tile

    // frag-read addressing (byte offsets; row stride 128 B)
    int aRow = ((wm << 6) + (l & 15)) << 7;
    int bRow = ((wn << 5) + (l & 15)) << 7;
    int sg0 = ((l >> 4) ^ (l & 7)) << 4;        // kk=0 swizzled seg
    int sg1 = sg0 ^ 64;                         // kk=1

    f32x4 acc[4][4][2];
    #pragma unroll
    for (int p = 0; p < 4; ++p)
        #pragma unroll
        for (int m = 0; m < 4; ++m)
            #pragma unroll
            for (int n = 0; n < 2; ++n) acc[p][m][n] = (f32x4){0.f, 0.f, 0.f, 0.f};

    bf16x8 af[4][2], bf0[2][2], bf1[2][2];

#define STG_A(ha, PARN, AOFF) do {                                          \
    const bf16* s_ = gA + (AOFF) + (ha) * 2 * HWPIC;                        \
    char* d_ = smem + (PARN) * 32768 + (ha) * 16384 + stW;                  \
    gll16(s_, d_); gll16(s_ + HWPIC, d_ + 8192); } while (0)
#define STG_B(hb, PARN, BOFF) do {                                          \
    const bf16* s_ = gB + (BOFF) + (hb) * (128 * IC);                       \
    char* d_ = smem + 65536 + (PARN) * 32768 + (hb) * 16384 + stW;          \
    gll16(s_, d_); gll16(s_ + 64 * IC, d_ + 8192); } while (0)
#define LD_A(QA) do { const char* Ab_ = Ap + (QA) * 16384 + aRow;           \
    _Pragma("unroll") for (int m_ = 0; m_ < 4; ++m_) {                      \
        af[m_][0] = *(const bf16x8*)(Ab_ + m_ * 2048 + sg0);                \
        af[m_][1] = *(const bf16x8*)(Ab_ + m_ * 2048 + sg1); } } while (0)
#define LD_B(DST, QB) do { const char* Bb_ = Bp + (QB) * 16384 + bRow;      \
    _Pragma("unroll") for (int n_ = 0; n_ < 2; ++n_) {                      \
        DST[n_][0] = *(const bf16x8*)(Bb_ + n_ * 2048 + sg0);               \
        DST[n_][1] = *(const bf16x8*)(Bb_ + n_ * 2048 + sg1); } } while (0)
#define MM(P, BF) do {                                                      \
    __builtin_amdgcn_s_setprio(1);                                          \
    _Pragma("unroll") for (int kk_ = 0; kk_ < 2; ++kk_)                     \
    _Pragma("unroll") for (int m_ = 0; m_ < 4; ++m_)                        \
    _Pragma("unroll") for (int n_ = 0; n_ < 2; ++n_)                        \
        acc[P][m_][n_] = __builtin_amdgcn_mfma_f32_16x16x32_bf16(           \
            af[m_][kk_], BF[n_][kk_], acc[P][m_][n_], 0, 0, 0);             \
    __builtin_amdgcn_s_setprio(0); } while (0)

    // prologue: stage tile 0 in order A0,B0,B1,A1; wait oldest 2 half-tiles
    STG_A(0, 0, 0);
    STG_B(0, 0, 0);
    STG_B(1, 0, 0);
    STG_A(1, 0, 0);
    VM4;
    BAR;

    #pragma clang loop unroll(disable)
    for (int T = 0; T < 35; ++T) {
        int par = T & 1, parn = par ^ 1;
        const char* Ap = smem + par * 32768;
        const char* Bp = smem + 65536 + par * 32768;
        int Tn = T + 1;
        int rn = Tn >> 2, icn = (Tn & 3) << 6;  // tap, 64-ic chunk of next tile
        int kyn = rn / 3, kxn = rn - kyn * 3;
        int aoffN = (kyn * HWP + kxn) * IC + icn;
        int boffN = (rn << 16) + icn;

        // p0: quadrant (A0,B0)
        LD_A(0); LD_B(bf0, 0);
        STG_A(0, parn, aoffN);
        BAR; MM(0, bf0); VM4; BAR;
        // p1: (A0,B1) — af reused
        LD_B(bf1, 1);
        STG_B(0, parn, boffN);
        BAR; MM(1, bf1); VM4; BAR;
        // p2: (A1,B1) — bf1 reused
        LD_A(1);
        STG_B(1, parn, boffN);
        BAR; MM(2, bf1); BAR;
        // p3: (A1,B0) — af and bf0 reused, no ds_reads
        STG_A(1, parn, aoffN);
        BAR; MM(3, bf0); VM4; BAR;
    }
    {   // tile 35 (par=1): no staging; drain counted 4->2->0
        const char* Ap = smem + 32768;
        const char* Bp = smem + 65536 + 32768;
        LD_A(0); LD_B(bf0, 0);
        MM(0, bf0); VM2; BAR;
        LD_B(bf1, 1);
        MM(1, bf1); VM0; BAR;
        LD_A(1);
        MM(2, bf1);
        MM(3, bf0);
    }

    // epilogue: D[row=(l>>4)*4+v][col=l&15]; 16B stores along spatial
    const float* dm = demod + nimg * OC;
    int ocol = l & 15, orow = (l >> 4) << 2;
    #pragma unroll
    for (int p = 0; p < 4; ++p) {
        int qa = p >> 1, qb = qa ^ (p & 1);     // (0,0)(0,1)(1,1)(1,0)
        #pragma unroll
        for (int n = 0; n < 2; ++n) {
            int oc = (qb << 7) + (wn << 5) + (n << 4) + ocol;
            float d = dm[oc];
            size_t ob = ((size_t)(nimg * OC + oc)) * SPATIAL
                      + spb + (qa << 7) + (wm << 6) + orow;
            #pragma unroll
            for (int m = 0; m < 4; ++m) {
                f32x4 a = acc[p][m][n];
                f32x4 o = { a[0] * d, a[1] * d, a[2] * d, a[3] * d };
                *reinterpret_cast<f32x4*>(out + ob + m * 16) = o;
            }
        }
    }
}

extern "C" void kernel_launch(void* const* d_in, const int* in_sizes, int n_in,
                              void* d_out, int out_size, void* d_ws, size_t ws_size,
                              hipStream_t stream) {
    const float* x      = (const float*)d_in[0];
    const float* style  = (const float*)d_in[1];
    const float* weight = (const float*)d_in[2];
    const float* mod_w  = (const float*)d_in[3];
    const float* mod_b  = (const float*)d_in[4];
    float* out = (float*)d_out;

    char* ws = (char*)d_ws;                  // ~37.2 MB
    float* scale = (float*)(ws + 0);         // 16 KB
    float* demod = (float*)(ws + 16384);     // 16 KB
    float* wsq   = (float*)(ws + 32768);     // 256 KB
    bf16*  wt2   = (bf16*)(ws + 294912);     // 1.18 MB [r][oc][ic]
    bf16*  xs    = (bf16*)(ws + 1474560);    // 35.7 MB padded NHWC

    static int s_attr = 0;
    if (!s_attr) {
        hipFuncSetAttribute(reinterpret_cast<const void*>(k_conv),
                            hipFuncAttributeMaxDynamicSharedMemorySize, 131072);
        s_attr = 1;
    }

    k_prep1<<<1808, 256, 0, stream>>>(weight, style, mod_w, mod_b,
                                      wsq, wt2, (uint4*)xs, scale);
    k_prep2<<<1040, 256, 0, stream>>>(x, scale, wsq, xs, demod);
    k_conv<<<256, 512, 131072, stream>>>(xs, wt2, demod, out);
}

// Round 2
// 186.158 us; speedup vs baseline: 1.0891x; 1.0219x over previous
//
#include <hip/hip_runtime.h>
#include <hip/hip_bf16.h>
#include <stdint.h>

// ModulatedConv2d: N=16, IC=OC=256, H=W=64, K=3, STYLE=512. fp32 in/out.
// out = demod[n,oc] * conv2d( x * (1+s)[n,ic], weight )   (StyleGAN2 identity)
// R6: k_conv 256x256 8-phase, now ONE barrier per phase ([LD;STG;VM4;BAR;MM]).
//     R5's [LD;STG;BAR;MM;VM4;BAR] lockstepped all 8 waves: shared 400-700cyc
//     LDS-queue drain before every MFMA window (measured phase 1145cyc vs 515
//     matrix). Dropping the post-MM barrier lets waves drift <=1 phase so one
//     wave's LD/STG overlaps another's MM. Hazard walk-through: every ds_read
//     is lgkm-drained by its own MM before the next BAR; every overwrite of a
//     region issues >=2 BARs after its last read; VM4 pre-BAR preserves
//     cross-wave staging visibility (drain targets unchanged: p0->prev B1,
//     p1->prev A1, p3->A0+B0).

#define NB  16
#define IC  256
#define OC  256
#define HW  64
#define HWP 66
#define SD  512
#define SPATIAL 4096
#define HWPIC 16896   // HWP*IC

typedef __hip_bfloat16 bf16;
typedef __bf16 bf16x8 __attribute__((ext_vector_type(8)));
typedef float  f32x4  __attribute__((ext_vector_type(4)));
typedef uint32_t u32a3 __attribute__((address_space(3)));
typedef const uint32_t u32a1 __attribute__((address_space(1)));

static __device__ __forceinline__ unsigned short f2bu(float f) {
    bf16 h = __float2bfloat16(f);
    union { bf16 b; unsigned short u; } c; c.b = h; return c.u;
}
static __device__ __forceinline__ void gll16(const void* g, void* l) {
    __builtin_amdgcn_global_load_lds((u32a1*)g, (u32a3*)l, 16, 0, 0);
}

// --- P1: fused prep. blocks [0,256): wt2/wsq; [256,784): border; [784,1808): scale
__global__ __launch_bounds__(256)
void k_prep1(const float* __restrict__ weight, const float* __restrict__ style,
             const float* __restrict__ mod_w, const float* __restrict__ mod_b,
             float* __restrict__ wsq, bf16* __restrict__ wt2,
             uint4* __restrict__ xs4, float* __restrict__ scale) {
    int b = blockIdx.x, t = threadIdx.x;
    if (b < 256) {
        // wsq[oc,ic] = sum_r w^2 ; wt2[r][oc][ic] = bf16(w)
        int tid = b * 256 + t;
        const float* wp = weight + (size_t)tid * 9;
        float v[9], s = 0.f;
        #pragma unroll
        for (int r = 0; r < 9; ++r) { v[r] = wp[r]; s += v[r] * v[r]; }
        wsq[tid] = s;
        #pragma unroll
        for (int r = 0; r < 9; ++r) wt2[(r << 16) + tid] = __float2bfloat16(v[r]);
    } else if (b < 784) {
        // zero 1-px border ring of padded NHWC xs
        int idx = b - 256;
        int n = idx / 33, bx = idx - n * 33;
        int f = bx * 256 + t;
        int u = f >> 5, q = f & 31;
        if (u >= 260) return;
        int rb;
        if      (u <  66) rb = u;
        else if (u < 132) rb = 65 * 66 + (u - 66);
        else if (u < 196) rb = (u - 131) * 66;
        else              rb = (u - 195) * 66 + 65;
        xs4[(size_t)n * 139392 + rb * 32 + q] = make_uint4(0u, 0u, 0u, 0u);
    } else {
        // scale[n,ic] = 1 + style[n,:].mod_w[ic,:] + mod_b[ic]; one wave/output
        int lane = t & 63;
        int w = (b - 784) * 4 + (t >> 6);
        int n = w >> 8, ic = w & 255;
        const float4* mw4 = (const float4*)mod_w + (size_t)ic * 128 + lane * 2;
        const float4* st4 = (const float4*)style + (size_t)n * 128 + lane * 2;
        float4 a0 = mw4[0], a1 = mw4[1], s0 = st4[0], s1 = st4[1];
        float acc = a0.x*s0.x + a0.y*s0.y + a0.z*s0.z + a0.w*s0.w
                  + a1.x*s1.x + a1.y*s1.y + a1.z*s1.z + a1.w*s1.w;
        #pragma unroll
        for (int off = 32; off > 0; off >>= 1) acc += __shfl_down(acc, off);
        if (lane == 0) scale[w] = acc + mod_b[ic] + 1.0f;
    }
}

// --- P2: blocks [0,1024): xs modulate+transpose; [1024,1040): demod ---------
// Transpose tile swizzled: ushort index sp*256 + (ic ^ ((sp>>2&7)<<3)).
__global__ __launch_bounds__(256)
void k_prep2(const float* __restrict__ x, const float* __restrict__ scale,
             const float* __restrict__ wsq, bf16* __restrict__ xs,
             float* __restrict__ demod) {
    __shared__ unsigned short tile[HW * 256];   // 32 KB; reused by demod path
    int b = blockIdx.x, t = threadIdx.x;
    if (b < 1024) {
        int y = b & 63, n = b >> 6;
        const float* sc = scale + n * IC;
        const float4* xp4 = (const float4*)(x + ((size_t)n * IC) * SPATIAL + (size_t)y * HW);
        #pragma unroll
        for (int i = 0; i < 16; ++i) {
            int fid = i * 256 + t;
            int ic = fid >> 4, f4 = fid & 15;
            float4 v = xp4[(size_t)ic * 1024 + f4];
            float s = sc[ic];
            int sp = f4 << 2;
            int sw = ic ^ ((f4 & 7) << 3);      // (sp>>2)&7 == f4&7 for all 4 rows
            tile[(sp + 0) * 256 + sw] = f2bu(v.x * s);
            tile[(sp + 1) * 256 + sw] = f2bu(v.y * s);
            tile[(sp + 2) * 256 + sw] = f2bu(v.z * s);
            tile[(sp + 3) * 256 + sw] = f2bu(v.w * s);
        }
        __syncthreads();
        uint4* dst4 = (uint4*)(xs + (((size_t)n * HWP + (y + 1)) * HWP + 1) * IC);
        #pragma unroll
        for (int j = 0; j < 8; ++j) {
            int uid = j * 256 + t;
            int sp = uid >> 5, g = uid & 31;
            dst4[sp * 32 + g] =
                *(const uint4*)&tile[sp * 256 + ((g ^ ((sp >> 2) & 7)) << 3)];
        }
    } else {
        // demod[n,oc] = rsqrt( sum_ic wsq[oc,ic]*scale[n,ic]^2 + eps )
        int n = b - 1024, oc = t;
        float* sc = (float*)tile;
        sc[t] = scale[n * IC + t];
        __syncthreads();
        const float4* wp4 = (const float4*)(wsq + (size_t)oc * IC);
        const float4* sc4 = (const float4*)sc;
        float acc = 0.f;
        #pragma unroll 8
        for (int i = 0; i < 64; ++i) {
            float4 q = wp4[i], s = sc4[i];
            acc += q.x*s.x*s.x + q.y*s.y*s.y + q.z*s.z*s.z + q.w*s.w*s.w;
        }
        demod[n * OC + oc] = rsqrtf(acc + 1e-8f);
    }
}

// --- K8: implicit-GEMM conv, 256x256 tile, BK=64, 8 waves (2Mx4N), 8-phase,
// ONE barrier per phase. LDS 128 KiB dynamic, XOR-seg swizzle conflict-free.
// Quadrant rotation (A0,B0)(A0,B1)(A1,B1)(A1,B0); tile t stages t+1 one
// half-tile per phase into the other parity; counted vmcnt, never 0 in loop.
#define VM4 asm volatile("s_waitcnt vmcnt(4)" ::: "memory")
#define VM2 asm volatile("s_waitcnt vmcnt(2)" ::: "memory")
#define VM0 asm volatile("s_waitcnt vmcnt(0)" ::: "memory")
#define BAR __builtin_amdgcn_s_barrier()

__global__ __launch_bounds__(512, 2)
void k_conv(const bf16* __restrict__ xs, const bf16* __restrict__ wt2,
            const float* __restrict__ demod, float* __restrict__ out) {
    extern __shared__ char smem[];              // 128 KiB
    int t = threadIdx.x, l = t & 63, w = t >> 6;
    int wm = w & 1, wn = w >> 1;
    int bid = blockIdx.x;
    int work = ((bid & 7) << 5) | (bid >> 3);   // XCD-contiguous: xcd*32 + slot
    int nimg = work >> 4;
    int ybase = (work & 15) << 2;               // 4 image rows per tile
    int spb = (work & 15) << 8;                 // 256 spatial positions

    // staging: half-tile = 128 rows x 64 k; wave w, lane l ->
    // row = w*8+(l>>3) (+64 for 2nd gll16), LDS seg l&7 holds global seg (l&7)^(l>>3).
    int srow = (w << 3) + (l >> 3);             // 0..63 (x coordinate)
    int gseg = (l & 7) ^ (l >> 3);
    const bf16* gA = xs + (((size_t)nimg * HWP + ybase) * HWP + srow) * IC + (gseg << 3);
    const bf16* gB = wt2 + ((size_t)srow << 8) + (gseg << 3);
    int stW = w << 10;                          // wave byte offset in half-tile

    // frag-read addressing (byte offsets; row stride 128 B)
    int aRow = ((wm << 6) + (l & 15)) << 7;
    int bRow = ((wn << 5) + (l & 15)) << 7;
    int sg0 = ((l >> 4) ^ (l & 7)) << 4;        // kk=0 swizzled seg
    int sg1 = sg0 ^ 64;                         // kk=1

    f32x4 acc[4][4][2];
    #pragma unroll
    for (int p = 0; p < 4; ++p)
        #pragma unroll
        for (int m = 0; m < 4; ++m)
            #pragma unroll
            for (int n = 0; n < 2; ++n) acc[p][m][n] = (f32x4){0.f, 0.f, 0.f, 0.f};

    bf16x8 af[4][2], bf0[2][2], bf1[2][2];

#define STG_A(ha, PARN, AOFF) do {                                          \
    const bf16* s_ = gA + (AOFF) + (ha) * 2 * HWPIC;                        \
    char* d_ = smem + (PARN) * 32768 + (ha) * 16384 + stW;                  \
    gll16(s_, d_); gll16(s_ + HWPIC, d_ + 8192); } while (0)
#define STG_B(hb, PARN, BOFF) do {                                          \
    const bf16* s_ = gB + (BOFF) + (hb) * (128 * IC);                       \
    char* d_ = smem + 65536 + (PARN) * 32768 + (hb) * 16384 + stW;          \
    gll16(s_, d_); gll16(s_ + 64 * IC, d_ + 8192); } while (0)
#define LD_A(QA) do { const char* Ab_ = Ap + (QA) * 16384 + aRow;           \
    _Pragma("unroll") for (int m_ = 0; m_ < 4; ++m_) {                      \
        af[m_][0] = *(const bf16x8*)(Ab_ + m_ * 2048 + sg0);                \
        af[m_][1] = *(const bf16x8*)(Ab_ + m_ * 2048 + sg1); } } while (0)
#define LD_B(DST, QB) do { const char* Bb_ = Bp + (QB) * 16384 + bRow;      \
    _Pragma("unroll") for (int n_ = 0; n_ < 2; ++n_) {                      \
        DST[n_][0] = *(const bf16x8*)(Bb_ + n_ * 2048 + sg0);               \
        DST[n_][1] = *(const bf16x8*)(Bb_ + n_ * 2048 + sg1); } } while (0)
#define MM(P, BF) do {                                                      \
    __builtin_amdgcn_s_setprio(1);                                          \
    _Pragma("unroll") for (int kk_ = 0; kk_ < 2; ++kk_)                     \
    _Pragma("unroll") for (int m_ = 0; m_ < 4; ++m_)                        \
    _Pragma("unroll") for (int n_ = 0; n_ < 2; ++n_)                        \
        acc[P][m_][n_] = __builtin_amdgcn_mfma_f32_16x16x32_bf16(           \
            af[m_][kk_], BF[n_][kk_], acc[P][m_][n_], 0, 0, 0);             \
    __builtin_amdgcn_s_setprio(0); } while (0)

    // prologue: stage tile 0 (A0,B0,B1,A1); drain A0,B0 before first LD
    STG_A(0, 0, 0);
    STG_B(0, 0, 0);
    STG_B(1, 0, 0);
    STG_A(1, 0, 0);
    VM4;
    BAR;

    #pragma clang loop unroll(disable)
    for (int T = 0; T < 35; ++T) {
        int par = T & 1, parn = par ^ 1;
        const char* Ap = smem + par * 32768;
        const char* Bp = smem + 65536 + par * 32768;
        int Tn = T + 1;
        int rn = Tn >> 2, icn = (Tn & 3) << 6;  // tap, 64-ic chunk of next tile
        int kyn = rn / 3, kxn = rn - kyn * 3;
        int aoffN = (kyn * HWP + kxn) * IC + icn;
        int boffN = (rn << 16) + icn;

        // p0: (A0,B0). VM4 drains prev-p2's B1 (read by p1's LD).
        LD_A(0); LD_B(bf0, 0);
        STG_A(0, parn, aoffN);
        VM4; BAR; MM(0, bf0);
        // p1: (A0,B1), af reused. VM4 drains prev-p3's A1 (read by p2's LD).
        LD_B(bf1, 1);
        STG_B(0, parn, boffN);
        VM4; BAR; MM(1, bf1);
        // p2: (A1,B1), bf1 reused. no wait.
        LD_A(1);
        STG_B(1, parn, boffN);
        BAR; MM(2, bf1);
        // p3: (A1,B0), regs only. VM4 drains p0's A0 + p1's B0 (next p0's LD).
        STG_A(1, parn, aoffN);
        VM4; BAR; MM(3, bf0);
    }
    {   // tile 35 (par=1): no staging; drain counted 4->2->0, pre-BAR
        const char* Ap = smem + 32768;
        const char* Bp = smem + 65536 + 32768;
        LD_A(0); LD_B(bf0, 0);
        VM2; BAR; MM(0, bf0);
        LD_B(bf1, 1);
        VM0; BAR; MM(1, bf1);
        LD_A(1);
        MM(2, bf1);
        MM(3, bf0);
    }

    // epilogue: D[row=(l>>4)*4+v][col=l&15]; 16B stores along spatial
    const float* dm = demod + nimg * OC;
    int ocol = l & 15, orow = (l >> 4) << 2;
    #pragma unroll
    for (int p = 0; p < 4; ++p) {
        int qa = p >> 1, qb = qa ^ (p & 1);     // (0,0)(0,1)(1,1)(1,0)
        #pragma unroll
        for (int n = 0; n < 2; ++n) {
            int oc = (qb << 7) + (wn << 5) + (n << 4) + ocol;
            float d = dm[oc];
            size_t ob = ((size_t)(nimg * OC + oc)) * SPATIAL
                      + spb + (qa << 7) + (wm << 6) + orow;
            #pragma unroll
            for (int m = 0; m < 4; ++m) {
                f32x4 a = acc[p][m][n];
                f32x4 o = { a[0] * d, a[1] * d, a[2] * d, a[3] * d };
                *reinterpret_cast<f32x4*>(out + ob + m * 16) = o;
            }
        }
    }
}

extern "C" void kernel_launch(void* const* d_in, const int* in_sizes, int n_in,
                              void* d_out, int out_size, void* d_ws, size_t ws_size,
                              hipStream_t stream) {
    const float* x      = (const float*)d_in[0];
    const float* style  = (const float*)d_in[1];
    const float* weight = (const float*)d_in[2];
    const float* mod_w  = (const float*)d_in[3];
    const float* mod_b  = (const float*)d_in[4];
    float* out = (float*)d_out;

    char* ws = (char*)d_ws;                  // ~37.2 MB
    float* scale = (float*)(ws + 0);         // 16 KB
    float* demod = (float*)(ws + 16384);     // 16 KB
    float* wsq   = (float*)(ws + 32768);     // 256 KB
    bf16*  wt2   = (bf16*)(ws + 294912);     // 1.18 MB [r][oc][ic]
    bf16*  xs    = (bf16*)(ws + 1474560);    // 35.7 MB padded NHWC

    static int s_attr = 0;
    if (!s_attr) {
        hipFuncSetAttribute(reinterpret_cast<const void*>(k_conv),
                            hipFuncAttributeMaxDynamicSharedMemorySize, 131072);
        s_attr = 1;
    }

    k_prep1<<<1808, 256, 0, stream>>>(weight, style, mod_w, mod_b,
                                      wsq, wt2, (uint4*)xs, scale);
    k_prep2<<<1040, 256, 0, stream>>>(x, scale, wsq, xs, demod);
    k_conv<<<256, 512, 131072, stream>>>(xs, wt2, demod, out);
}